// Round 9
// baseline (1107.650 us; speedup 1.0000x reference)
//
#include <hip/hip_runtime.h>
#include <stdint.h>

#define BB 8
#define NN 4096
#define MM 1366   // len(arange(0,4096,3))
#define NS 32
#define RAD2 0.01f
#define SCAP 96   // survivor cap per (query, big-chunk)

__device__ __forceinline__ float rl(float v, int l) {
    return __int_as_float(__builtin_amdgcn_readlane(__float_as_int(v), l));
}
__device__ __forceinline__ uint32_t um(uint32_t a, uint32_t b) { return a < b ? a : b; }
__device__ __forceinline__ uint32_t ux(uint32_t a, uint32_t b) { return a > b ? a : b; }
__device__ __forceinline__ uint32_t um3(uint32_t a, uint32_t b, uint32_t c) { return um(um(a, b), c); }

// merge sorted pair (s0<=s1) into sorted-10 kk
__device__ __forceinline__ void mrg2(uint32_t* kk, uint32_t s0, uint32_t s1) {
    uint32_t n0 = um(kk[0], s0);
    uint32_t n1 = um3(kk[1], ux(kk[0], s0), s1);
    uint32_t n2 = um3(kk[2], ux(kk[1], s0), ux(kk[0], s1));
    uint32_t n3 = um3(kk[3], ux(kk[2], s0), ux(kk[1], s1));
    uint32_t n4 = um3(kk[4], ux(kk[3], s0), ux(kk[2], s1));
    uint32_t n5 = um3(kk[5], ux(kk[4], s0), ux(kk[3], s1));
    uint32_t n6 = um3(kk[6], ux(kk[5], s0), ux(kk[4], s1));
    uint32_t n7 = um3(kk[7], ux(kk[6], s0), ux(kk[5], s1));
    uint32_t n8 = um3(kk[8], ux(kk[7], s0), ux(kk[6], s1));
    uint32_t n9 = um3(kk[9], ux(kk[8], s0), ux(kk[7], s1));
    kk[0]=n0; kk[1]=n1; kk[2]=n2; kk[3]=n3; kk[4]=n4;
    kk[5]=n5; kk[6]=n6; kk[7]=n7; kk[8]=n8; kk[9]=n9;
}

// merge sorted quad (s0<=s1<=s2<=s3) into sorted-10 kk
__device__ __forceinline__ void mrg4(uint32_t* kk, uint32_t s0, uint32_t s1,
                                     uint32_t s2, uint32_t s3) {
    uint32_t n0 = um(kk[0], s0);
    uint32_t n1 = um3(kk[1], ux(kk[0], s0), s1);
    uint32_t n2 = um(um3(kk[2], ux(kk[1], s0), ux(kk[0], s1)), s2);
    uint32_t n3 = um3(um3(kk[3], ux(kk[2], s0), ux(kk[1], s1)), ux(kk[0], s2), s3);
    uint32_t n4 = um3(um3(kk[4], ux(kk[3], s0), ux(kk[2], s1)), ux(kk[1], s2), ux(kk[0], s3));
    uint32_t n5 = um3(um3(kk[5], ux(kk[4], s0), ux(kk[3], s1)), ux(kk[2], s2), ux(kk[1], s3));
    uint32_t n6 = um3(um3(kk[6], ux(kk[5], s0), ux(kk[4], s1)), ux(kk[3], s2), ux(kk[2], s3));
    uint32_t n7 = um3(um3(kk[7], ux(kk[6], s0), ux(kk[5], s1)), ux(kk[4], s2), ux(kk[3], s3));
    uint32_t n8 = um3(um3(kk[8], ux(kk[7], s0), ux(kk[6], s1)), ux(kk[5], s2), ux(kk[4], s3));
    uint32_t n9 = um3(um3(kk[9], ux(kk[8], s0), ux(kk[7], s1)), ux(kk[6], s2), ux(kk[5], s3));
    kk[0]=n0; kk[1]=n1; kk[2]=n2; kk[3]=n3; kk[4]=n4;
    kk[5]=n5; kk[6]=n6; kk[7]=n7; kk[8]=n8; kk[9]=n9;
}

// sort 4 keys ascending: 5-CE network
__device__ __forceinline__ void srt4(uint32_t& a, uint32_t& b, uint32_t& c, uint32_t& d) {
    uint32_t t0 = um(a, b), t1 = ux(a, b), t2 = um(c, d), t3 = ux(c, d);
    uint32_t s0 = um(t0, t2), m0 = ux(t0, t2), m1 = um(t1, t3), s3 = ux(t1, t3);
    a = s0; b = um(m0, m1); c = ux(m0, m1); d = s3;
}

// sorted ascending top-10 insert: 19 min/max ops, chain depth 2
__device__ __forceinline__ void ins10(uint32_t* kk, uint32_t x) {
    uint32_t t0 = kk[0];
    kk[0] = um(kk[0], x);
    #pragma unroll
    for (int r = 1; r < 10; ++r) {
        uint32_t xr = ux(t0, x);
        t0 = kk[r];
        kk[r] = um(kk[r], xr);
    }
}

__device__ __forceinline__ uint32_t dkey(const float4& c, float px, float py,
                                         float pz, float pa, int idx) {
    float dot = fmaf(pz, c.z, fmaf(py, c.y, px * c.x));
    float dd = fmaxf(fmaf(-2.f, dot, pa + c.w), 0.f);
    return (__float_as_uint(dd) & 0xFFFFF000u) | (uint32_t)idx;
}

// ---------------- K0: prep ----------------
__global__ __launch_bounds__(256) void k_prep(const float* __restrict__ data,
                                              float* __restrict__ out,
                                              float4* __restrict__ cand4) {
    int t = blockIdx.x * 256 + threadIdx.x;   // BB*NN
    float x = data[t * 3], y = data[t * 3 + 1], z = data[t * 3 + 2];
    out[t * 3] = x; out[t * 3 + 1] = y; out[t * 3 + 2] = z;
    cand4[t] = make_float4(x, y, z, x * x + y * y + z * z);
}

// ---------------- K1: stem ----------------
__global__ __launch_bounds__(256) void k_stem(const float* __restrict__ data,
                                              const float* __restrict__ Ws,
                                              const float* __restrict__ bs,
                                              float* __restrict__ f0) {
    int t = blockIdx.x * 256 + threadIdx.x;
    int c = t & 63;
    int r = t >> 6;
    const float* d = data + r * 3;
    float acc = bs[c];
    acc = fmaf(d[0], Ws[c], acc);
    acc = fmaf(d[1], Ws[64 + c], acc);
    acc = fmaf(d[2], Ws[128 + c], acc);
    f0[t] = fmaxf(acc, 0.f);
}

// ---------------- A: exact sorted-10 over subset (first 256 cands, 4x64) ----------------
__global__ __launch_bounds__(256) void k_knn_sub(const float4* __restrict__ cand4,
                                                 uint32_t* __restrict__ pk) {
    int t = threadIdx.x;
    int blk = blockIdx.x;          // BB*16*4 = 512
    int ch = blk & 3;
    int pg = (blk >> 2) & 15;
    int b = blk >> 6;
    const float4* cb = cand4 + b * NN;
    int c0 = ch * 64;
    int q = b * NN + pg * 256 + t;
    float4 me = cb[pg * 256 + t];
    float px = me.x, py = me.y, pz = me.z, pa = me.w;
    uint32_t kk[10];
    #pragma unroll
    for (int r = 0; r < 10; ++r) kk[r] = 0xFFFFFF00u + r;
    for (int j = 0; j < 64; j += 4) {
        uint32_t ka = dkey(cb[c0 + j],     px, py, pz, pa, c0 + j);
        uint32_t kb = dkey(cb[c0 + j + 1], px, py, pz, pa, c0 + j + 1);
        uint32_t kc = dkey(cb[c0 + j + 2], px, py, pz, pa, c0 + j + 2);
        uint32_t kd = dkey(cb[c0 + j + 3], px, py, pz, pa, c0 + j + 3);
        srt4(ka, kb, kc, kd);
        mrg4(kk, ka, kb, kc, kd);
    }
    #pragma unroll
    for (int r = 0; r < 10; ++r)
        pk[(ch * 10 + r) * (BB * NN) + q] = kk[r];
}

// ---------------- B: threshold filter scan ----------------
// T = 10th-smallest subset key (upper bound of global 10th). Survivors
// (key <= T, exact uint compare) superset the true top-10. Store u16 indices.
__global__ __launch_bounds__(256) void k_knn_filt(const float4* __restrict__ cand4,
                                                  const uint32_t* __restrict__ pk,
                                                  unsigned short* __restrict__ sk,
                                                  unsigned short* __restrict__ cnts) {
    int t = threadIdx.x;
    int blk = blockIdx.x;          // BB*16*4 = 512
    int ch = blk & 3;
    int pg = (blk >> 2) & 15;
    int b = blk >> 6;
    const float4* cb = cand4 + b * NN;
    int q = b * NN + pg * 256 + t;
    float4 me = cb[pg * 256 + t];
    float px = me.x, py = me.y, pz = me.z, pa = me.w;
    uint32_t kk[10];
    #pragma unroll
    for (int r = 0; r < 10; ++r) kk[r] = pk[r * (BB * NN) + q];
    for (int s = 1; s < 4; ++s) {
        uint32_t sv[10];
        #pragma unroll
        for (int r = 0; r < 10; ++r) sv[r] = pk[(s * 10 + r) * (BB * NN) + q];
        mrg4(kk, sv[0], sv[1], sv[2], sv[3]);
        mrg4(kk, sv[4], sv[5], sv[6], sv[7]);
        mrg2(kk, sv[8], sv[9]);
    }
    uint32_t T = kk[9];
    int c0 = ch * 1024;
    uint32_t cnt = 0;
    for (int j = 0; j < 1024; ++j) {
        uint32_t key = dkey(cb[c0 + j], px, py, pz, pa, c0 + j);
        if (key <= T) {
            if (cnt < SCAP) sk[(ch * SCAP + cnt) * (BB * NN) + q] = (unsigned short)(c0 + j);
            cnt++;
        }
    }
    cnts[ch * (BB * NN) + q] = (unsigned short)cnt;
}

// ---------------- C: ladder survivors -> exact top-10 -> cov/eig/MLP + mrg ----------------
__device__ __forceinline__ void jrot(float& app, float& aqq, float& apq,
                                     float& arp, float& arq) {
    float ap = apq;
    if (fabsf(ap) > 1e-32f) {
        float th = (aqq - app) / (2.f * ap);
        float t = 1.f / (fabsf(th) + sqrtf(th * th + 1.f));
        t = th < 0.f ? -t : t;
        float c = 1.f / sqrtf(t * t + 1.f);
        float s = t * c;
        app = app - t * ap;
        aqq = aqq + t * ap;
        apq = 0.f;
        float rp = arp, rq = arq;
        arp = c * rp - s * rq;
        arq = s * rp + c * rq;
    }
}

__global__ __launch_bounds__(256) void k_knn_meig(const float4* __restrict__ cand4,
                                                  const unsigned short* __restrict__ sk,
                                                  const unsigned short* __restrict__ cnts,
                                                  uint32_t* __restrict__ mrg,
                                                  const float* __restrict__ We1,
                                                  const float* __restrict__ be1,
                                                  const float* __restrict__ We2,
                                                  const float* __restrict__ be2,
                                                  float* __restrict__ ef) {
    int q = blockIdx.x * 256 + threadIdx.x;   // B*N
    int b = q >> 12;
    const float4* cb = cand4 + b * NN;
    float4 me = cb[q & (NN - 1)];
    float px = me.x, py = me.y, pz = me.z, pa = me.w;
    uint32_t kk[10];
    #pragma unroll
    for (int r = 0; r < 10; ++r) kk[r] = 0xFFFFFF00u + r;
    bool ovf = false;
    for (int ch = 0; ch < 4; ++ch) {
        int cnt = cnts[ch * (BB * NN) + q];
        if (cnt > SCAP) { ovf = true; cnt = 0; }
        for (int s = 0; s < cnt; ++s) {
            int idx = sk[(ch * SCAP + s) * (BB * NN) + q];
            ins10(kk, dkey(cb[idx], px, py, pz, pa, idx));
        }
    }
    if (ovf) {   // essentially-never fallback: exact full scan
        #pragma unroll
        for (int r = 0; r < 10; ++r) kk[r] = 0xFFFFFF00u + r;
        for (int j = 0; j < NN; ++j)
            ins10(kk, dkey(cb[j], px, py, pz, pa, j));
    }
    #pragma unroll
    for (int r = 0; r < 10; ++r)
        mrg[r * (BB * NN) + q] = kk[r];     // merged sorted-10 for k_sa
    float xs[10], ys[10], zs[10];
    float mx = 0.f, my = 0.f, mz = 0.f;
    #pragma unroll
    for (int r = 0; r < 10; ++r) {
        int n = (int)(kk[r] & 0xFFFu);
        float4 cr = cb[n];
        xs[r] = cr.x; ys[r] = cr.y; zs[r] = cr.z;
        mx += xs[r]; my += ys[r]; mz += zs[r];
    }
    mx *= 0.1f; my *= 0.1f; mz *= 0.1f;
    float a00 = 0, a01 = 0, a02 = 0, a11 = 0, a12 = 0, a22 = 0;
    #pragma unroll
    for (int r = 0; r < 10; ++r) {
        float x = xs[r] - mx, y = ys[r] - my, z = zs[r] - mz;
        a00 = fmaf(x, x, a00); a01 = fmaf(x, y, a01); a02 = fmaf(x, z, a02);
        a11 = fmaf(y, y, a11); a12 = fmaf(y, z, a12); a22 = fmaf(z, z, a22);
    }
    a00 *= 0.1f; a01 *= 0.1f; a02 *= 0.1f; a11 *= 0.1f; a12 *= 0.1f; a22 *= 0.1f;
    #pragma unroll
    for (int sweep = 0; sweep < 6; ++sweep) {
        jrot(a00, a11, a01, a02, a12);
        jrot(a00, a22, a02, a01, a12);
        jrot(a11, a22, a12, a01, a02);
    }
    float e0 = a00, e1 = a11, e2 = a22, tmp;
    if (e0 > e1) { tmp = e0; e0 = e1; e1 = tmp; }
    if (e1 > e2) { tmp = e1; e1 = e2; e2 = tmp; }
    if (e0 > e1) { tmp = e0; e0 = e1; e1 = tmp; }
    float tt[4];
    #pragma unroll
    for (int i = 0; i < 4; ++i) {
        float v = be1[i];
        v = fmaf(e0, We1[i], v);
        v = fmaf(e1, We1[4 + i], v);
        v = fmaf(e2, We1[8 + i], v);
        tt[i] = fmaxf(v, 0.f);
    }
    #pragma unroll
    for (int i = 0; i < 4; ++i) {
        float v = be2[i];
        v = fmaf(tt[0], We2[i], v);
        v = fmaf(tt[1], We2[4 + i], v);
        v = fmaf(tt[2], We2[8 + i], v);
        v = fmaf(tt[3], We2[12 + i], v);
        ef[q * 4 + i] = v;
    }
}

// ---------------- K2: ball query (via merged 10-NN) + SA MLP + maxpool ----------------
__global__ __launch_bounds__(256) void k_sa(const float4* __restrict__ cand4,
                                            const float* __restrict__ data,
                                            const float* __restrict__ f0,
                                            const uint32_t* __restrict__ mrg,
                                            const float* __restrict__ Wsa,
                                            const float* __restrict__ bsa,
                                            float* __restrict__ fsub) {
    __shared__ float2 sW[67 * 64];
    __shared__ int sIdx[4][NS];
    for (int i = threadIdx.x; i < 67 * 64; i += 256) {
        int k = i >> 6, c = i & 63;
        sW[i] = make_float2(Wsa[k * 128 + c], Wsa[k * 128 + 64 + c]);
    }
    __syncthreads();
    int wv = threadIdx.x >> 6, lane = threadIdx.x & 63;
    int gm = blockIdx.x * 4 + wv;
    if (gm >= BB * MM) return;
    int b = gm / MM, m = gm - b * MM;
    const float4* cb4 = cand4 + b * NN;
    const float* db = data + b * NN * 3;
    float4 cen = cb4[3 * m];
    float cx = cen.x, cy = cen.y, cz = cen.z, sa = cen.w;

    int cnt;
    bool fallback;
    {
        float d2l = 1e30f;
        int idxl = 0;
        if (lane < 10) {
            uint32_t key = mrg[lane * (BB * NN) + b * NN + 3 * m];
            idxl = (int)(key & 0xFFFu);
            float4 c = cb4[idxl];
            float dot = fmaf(cz, c.z, fmaf(cy, c.y, cx * c.x));
            d2l = (sa + c.w) - 2.f * dot;
        }
        bool valid = (lane < 10) && (d2l < RAD2);
        unsigned long long mask = __ballot(valid);
        if (valid) sIdx[wv][__popcll(mask & ((1ull << lane) - 1ull))] = idxl;
        cnt = __popcll(mask);
        fallback = rl(d2l, 9) < RAD2 * 1.0005f;
    }
    if (fallback) {
        cnt = 0;
        for (int base = 0; base < NN; base += 64) {
            int n = base + lane;
            float4 c = cb4[n];
            float dot = fmaf(cz, c.z, fmaf(cy, c.y, cx * c.x));
            float d2 = (sa + c.w) - 2.f * dot;
            bool valid = d2 < RAD2;
            unsigned long long mask = __ballot(valid);
            if (valid) {
                int pos = cnt + __popcll(mask & ((1ull << lane) - 1ull));
                if (pos < NS) sIdx[wv][pos] = n;
            }
            cnt += __popcll(mask);
            if (cnt >= NS) break;
        }
    }
    int scnt = cnt < NS ? cnt : NS;

    float cl = lane == 0 ? cx : (lane == 1 ? cy : cz);
    float hb0 = bsa[lane], hb1 = bsa[64 + lane];
    float m0 = 0.f, m1 = 0.f;

    for (int s0 = 0; s0 < scnt; s0 += 4) {
        float fr[4], fr2[4];
        #pragma unroll
        for (int u = 0; u < 4; ++u) {
            int s = s0 + u;
            if (s >= scnt) s = 0;
            int nj = sIdx[wv][s];
            int fb = (b * NN + nj) * 64;
            float v;
            if (lane >= 3) v = f0[fb + lane - 3];
            else           v = (db[nj * 3 + lane] - cl) * 10.0f;
            fr[u] = v;
            fr2[u] = (lane < 3) ? f0[fb + 61 + lane] : 0.f;
        }
        float h0[4], h1[4];
        #pragma unroll
        for (int u = 0; u < 4; ++u) { h0[u] = hb0; h1[u] = hb1; }
        for (int k = 0; k < 64; ++k) {
            float2 w = sW[k * 64 + lane];
            #pragma unroll
            for (int u = 0; u < 4; ++u) {
                float fv = rl(fr[u], k);
                h0[u] = fmaf(fv, w.x, h0[u]);
                h1[u] = fmaf(fv, w.y, h1[u]);
            }
        }
        #pragma unroll
        for (int k = 64; k < 67; ++k) {
            float2 w = sW[k * 64 + lane];
            #pragma unroll
            for (int u = 0; u < 4; ++u) {
                float fv = rl(fr2[u], k - 64);
                h0[u] = fmaf(fv, w.x, h0[u]);
                h1[u] = fmaf(fv, w.y, h1[u]);
            }
        }
        #pragma unroll
        for (int u = 0; u < 4; ++u) {
            m0 = fmaxf(m0, fmaxf(h0[u], 0.f));
            m1 = fmaxf(m1, fmaxf(h1[u], 0.f));
        }
    }
    fsub[gm * 128 + lane] = m0;
    fsub[gm * 128 + 64 + lane] = m1;
}

// ---------------- K3: 3-NN among centers + inverse-distance interp ----------------
__global__ __launch_bounds__(512) void k_interp(const float4* __restrict__ cand4,
                                                const float* __restrict__ fsub,
                                                float* __restrict__ itp) {
    __shared__ float4 sC[MM];
    __shared__ float sMD[8][64][3];
    __shared__ int   sMI[8][64][3];
    __shared__ float sWts[64][3];
    __shared__ int   sNbr[64][3];
    int t = threadIdx.x, wv = t >> 6, lane = t & 63;
    int blk = blockIdx.x;
    int b = blk >> 6;
    int pbase = (blk & 63) * 64;
    const float4* cb4 = cand4 + b * NN;
    for (int m = t; m < MM; m += 512) sC[m] = cb4[3 * m];
    __syncthreads();
    int p = pbase + lane;
    float4 pm = cb4[p];
    float px = pm.x, py = pm.y, pz = pm.z, pa = pm.w;
    float d0 = 1e30f, d1 = 1e30f, d2v = 1e30f;
    int n0 = 0, n1 = 0, n2 = 0;
    int ms = wv * 171, me = ms + 171 < MM ? ms + 171 : MM;
    for (int m = ms; m < me; ++m) {
        float4 c = sC[m];
        float dd = (pa + c.w) - 2.f * (px * c.x + py * c.y + pz * c.z);
        if (dd < d2v) {
            if (dd < d1) {
                d2v = d1; n2 = n1;
                if (dd < d0) { d1 = d0; n1 = n0; d0 = dd; n0 = m; }
                else         { d1 = dd; n1 = m; }
            } else { d2v = dd; n2 = m; }
        }
    }
    sMD[wv][lane][0] = d0; sMD[wv][lane][1] = d1; sMD[wv][lane][2] = d2v;
    sMI[wv][lane][0] = n0; sMI[wv][lane][1] = n1; sMI[wv][lane][2] = n2;
    __syncthreads();
    if (wv == 0) {
        d0 = sMD[0][lane][0]; d1 = sMD[0][lane][1]; d2v = sMD[0][lane][2];
        n0 = sMI[0][lane][0]; n1 = sMI[0][lane][1]; n2 = sMI[0][lane][2];
        for (int w = 1; w < 8; ++w) {
            #pragma unroll
            for (int r = 0; r < 3; ++r) {
                float dd = sMD[w][lane][r];
                int mm = sMI[w][lane][r];
                if (dd < d2v) {
                    if (dd < d1) {
                        d2v = d1; n2 = n1;
                        if (dd < d0) { d1 = d0; n1 = n0; d0 = dd; n0 = mm; }
                        else         { d1 = dd; n1 = mm; }
                    } else { d2v = dd; n2 = mm; }
                }
            }
        }
        float w0 = 1.f / (d0 + 1e-8f), w1 = 1.f / (d1 + 1e-8f), w2 = 1.f / (d2v + 1e-8f);
        float ws = w0 + w1 + w2;
        sWts[lane][0] = w0 / ws; sWts[lane][1] = w1 / ws; sWts[lane][2] = w2 / ws;
        sNbr[lane][0] = n0; sNbr[lane][1] = n1; sNbr[lane][2] = n2;
    }
    __syncthreads();
    for (int i = wv * 8; i < wv * 8 + 8; ++i) {
        float a0 = sWts[i][0], a1 = sWts[i][1], a2 = sWts[i][2];
        const float* r0 = fsub + (b * MM + sNbr[i][0]) * 128;
        const float* r1 = fsub + (b * MM + sNbr[i][1]) * 128;
        const float* r2 = fsub + (b * MM + sNbr[i][2]) * 128;
        float v0 = fmaf(a2, r2[lane], fmaf(a1, r1[lane], a0 * r0[lane]));
        float v1 = fmaf(a2, r2[64 + lane], fmaf(a1, r1[64 + lane], a0 * r0[64 + lane]));
        int row = b * NN + pbase + i;
        itp[row * 128 + lane] = v0;
        itp[row * 128 + 64 + lane] = v1;
    }
}

// ---------------- K5: f = relu([interp, f0] @ W_fp + b_fp) ----------------
__global__ __launch_bounds__(256) void k_fp(const float* __restrict__ itp,
                                            const float* __restrict__ f0,
                                            const float* __restrict__ W,
                                            const float* __restrict__ bias,
                                            float* __restrict__ outf) {
    __shared__ float sW[192 * 64];
    for (int i = threadIdx.x; i < 192 * 64; i += 256) sW[i] = W[i];
    __syncthreads();
    int lane = threadIdx.x & 63;
    int wv = threadIdx.x >> 6;
    float bb = bias[lane];
    int rowbase = blockIdx.x * 64 + wv * 16;
    for (int it = 0; it < 4; ++it) {
        int r = rowbase + it * 4;
        float fa[4], fbv[4], fc[4], acc[4];
        #pragma unroll
        for (int u = 0; u < 4; ++u) {
            fa[u]  = itp[(r + u) * 128 + lane];
            fbv[u] = itp[(r + u) * 128 + 64 + lane];
            fc[u]  = f0[(r + u) * 64 + lane];
            acc[u] = bb;
        }
        #pragma unroll
        for (int k = 0; k < 192; ++k) {
            float w = sW[k * 64 + lane];
            #pragma unroll
            for (int u = 0; u < 4; ++u) {
                float fv = k < 64 ? rl(fa[u], k)
                         : (k < 128 ? rl(fbv[u], k - 64) : rl(fc[u], k - 128));
                acc[u] = fmaf(fv, w, acc[u]);
            }
        }
        #pragma unroll
        for (int u = 0; u < 4; ++u)
            outf[(r + u) * 64 + lane] = fmaxf(acc[u], 0.f);
    }
}

// ---------------- K6: zc = [f, ef] @ W_fin + b_fin ----------------
__global__ __launch_bounds__(256) void k_fin(const float* __restrict__ fb,
                                             const float* __restrict__ efb,
                                             const float* __restrict__ W,
                                             const float* __restrict__ bias,
                                             float* __restrict__ zc) {
    __shared__ float sW[68 * 64];
    for (int i = threadIdx.x; i < 68 * 64; i += 256) sW[i] = W[i];
    __syncthreads();
    int lane = threadIdx.x & 63;
    int wv = threadIdx.x >> 6;
    float bb = bias[lane];
    int rowbase = blockIdx.x * 64 + wv * 16;
    for (int it = 0; it < 4; ++it) {
        int r = rowbase + it * 4;
        float fa[4], fe[4], acc[4];
        #pragma unroll
        for (int u = 0; u < 4; ++u) {
            fa[u] = fb[(r + u) * 64 + lane];
            fe[u] = (lane < 4) ? efb[(r + u) * 4 + lane] : 0.f;
            acc[u] = bb;
        }
        #pragma unroll
        for (int k = 0; k < 68; ++k) {
            float w = sW[k * 64 + lane];
            #pragma unroll
            for (int u = 0; u < 4; ++u) {
                float fv = k < 64 ? rl(fa[u], k) : rl(fe[u], k - 64);
                acc[u] = fmaf(fv, w, acc[u]);
            }
        }
        #pragma unroll
        for (int u = 0; u < 4; ++u)
            zc[(r + u) * 64 + lane] = acc[u];
    }
}

// ---------------- K7: batchnorm stats, two-stage ----------------
__global__ __launch_bounds__(256) void k_stats1(const float* __restrict__ zc,
                                                float* __restrict__ pp) {
    int t = threadIdx.x;
    int c = t & 63, r4 = t >> 6;
    float s = 0.f, sq = 0.f;
    int base = blockIdx.x * 512;
    for (int i = 0; i < 128; ++i) {
        float v = zc[(base + i * 4 + r4) * 64 + c];
        s += v;
        sq = fmaf(v, v, sq);
    }
    __shared__ float ls[256], lq[256];
    ls[t] = s; lq[t] = sq;
    __syncthreads();
    if (t < 64) {
        float st = ls[t] + ls[t + 64] + ls[t + 128] + ls[t + 192];
        float qt = lq[t] + lq[t + 64] + lq[t + 128] + lq[t + 192];
        pp[blockIdx.x * 128 + t] = st;
        pp[blockIdx.x * 128 + 64 + t] = qt;
    }
}

__global__ __launch_bounds__(64) void k_stats2(const float* __restrict__ pp,
                                               const float* __restrict__ gamma,
                                               const float* __restrict__ beta,
                                               float* __restrict__ ss) {
    int c = threadIdx.x;
    float s = 0.f, sq = 0.f;
    for (int k = 0; k < 64; ++k) {
        s += pp[k * 128 + c];
        sq += pp[k * 128 + 64 + c];
    }
    const float inv = 1.f / (float)(BB * NN);
    float mu = s * inv;
    float var = sq * inv - mu * mu;
    float sc = gamma[c] / sqrtf(var + 1e-5f);
    ss[c] = sc;
    ss[64 + c] = beta[c] - mu * sc;
}

// ---------------- K8: normalize + relu + transpose ----------------
__global__ __launch_bounds__(256) void k_norm_t(const float* __restrict__ zc,
                                                const float* __restrict__ ss,
                                                float* __restrict__ out) {
    __shared__ float sT[64][65];
    int blk = blockIdx.x;
    int b = blk >> 6;
    int nbase = (blk & 63) * 64;
    int c = threadIdx.x & 63;
    int r4 = threadIdx.x >> 6;
    float sc = ss[c], sh = ss[64 + c];
    #pragma unroll
    for (int i = 0; i < 16; ++i) {
        int nr = i * 4 + r4;
        float v = zc[(b * NN + nbase + nr) * 64 + c];
        sT[nr][c] = fmaxf(fmaf(v, sc, sh), 0.f);
    }
    __syncthreads();
    int nn = threadIdx.x & 63;
    #pragma unroll
    for (int i = 0; i < 16; ++i) {
        int cc = i * 4 + r4;
        out[BB * NN * 3 + (b * 64 + cc) * NN + nbase + nn] = sT[nn][cc];
    }
}

extern "C" void kernel_launch(void* const* d_in, const int* in_sizes, int n_in,
                              void* d_out, int out_size, void* d_ws, size_t ws_size,
                              hipStream_t stream) {
    const float* data = (const float*)d_in[0];
    const float* Wst  = (const float*)d_in[2];
    const float* bst  = (const float*)d_in[3];
    const float* Wsa  = (const float*)d_in[4];
    const float* bsa  = (const float*)d_in[5];
    const float* Wfp  = (const float*)d_in[6];
    const float* bfp  = (const float*)d_in[7];
    const float* We1  = (const float*)d_in[8];
    const float* be1  = (const float*)d_in[9];
    const float* We2  = (const float*)d_in[10];
    const float* be2  = (const float*)d_in[11];
    const float* Wfin = (const float*)d_in[12];
    const float* bfin = (const float*)d_in[13];
    const float* gamma = (const float*)d_in[14];
    const float* beta  = (const float*)d_in[15];
    float* out = (float*)d_out;

    // layout (floats)
    float* f0   = (float*)d_ws;            // 2,097,152
    float* fsub = f0 + 2097152;            // 1,398,784
    float* efb  = fsub + 1398784;          //   131,072
    float* zc   = efb + 131072;            // 2,097,152
    float* ss   = zc + 2097152;            //       128
    float* pp   = ss + 128;                //     8,192
    float* cntf = pp + 8192;               //    65,536 (cnts u16: 4*32768*2B)
    float4* cand4 = (float4*)(cntf + 65536);               // 131,072 floats
    uint32_t* mrgb = (uint32_t*)((float*)cand4 + 131072);  // 1,310,720 u32
    float* itp  = (float*)mrgb + 1310720;  // 4,194,304
    float* fb   = itp + 4194304;           // 2,097,152
    // aliases (consumed before itp/fb/mrgb are written):
    uint32_t* pkk = (uint32_t*)mrgb;       // A's 4*10*32768 u32 == mrgb size
    unsigned short* sk = (unsigned short*)itp;   // 4*96*32768 u16 = 24 MB <= itp+fb
    unsigned short* cnts = (unsigned short*)cntf;

    k_prep<<<(BB * NN) / 256, 256, 0, stream>>>(data, out, cand4);
    k_stem<<<(BB * NN * 64) / 256, 256, 0, stream>>>(data, Wst, bst, f0);
    k_knn_sub<<<BB * 16 * 4, 256, 0, stream>>>(cand4, pkk);
    k_knn_filt<<<BB * 16 * 4, 256, 0, stream>>>(cand4, pkk, sk, cnts);
    k_knn_meig<<<(BB * NN) / 256, 256, 0, stream>>>(cand4, sk, cnts, mrgb,
                                                    We1, be1, We2, be2, efb);
    k_sa<<<(BB * MM + 3) / 4, 256, 0, stream>>>(cand4, data, f0, mrgb, Wsa, bsa, fsub);
    k_interp<<<BB * 64, 512, 0, stream>>>(cand4, fsub, itp);
    k_fp<<<512, 256, 0, stream>>>(itp, f0, Wfp, bfp, fb);
    k_fin<<<512, 256, 0, stream>>>(fb, efb, Wfin, bfin, zc);
    k_stats1<<<64, 256, 0, stream>>>(zc, pp);
    k_stats2<<<1, 64, 0, stream>>>(pp, gamma, beta, ss);
    k_norm_t<<<512, 256, 0, stream>>>(zc, ss, out);
}

// Round 10
// 594.445 us; speedup vs baseline: 1.8633x; 1.8633x over previous
//
#include <hip/hip_runtime.h>
#include <stdint.h>

#define BB 8
#define NN 4096
#define MM 1366   // len(arange(0,4096,3))
#define NS 32
#define RAD2 0.01f
#define SCAP 96   // survivor cap per (query, big-chunk)

__device__ __forceinline__ float rl(float v, int l) {
    return __int_as_float(__builtin_amdgcn_readlane(__float_as_int(v), l));
}
__device__ __forceinline__ uint32_t um(uint32_t a, uint32_t b) { return a < b ? a : b; }
__device__ __forceinline__ uint32_t ux(uint32_t a, uint32_t b) { return a > b ? a : b; }
__device__ __forceinline__ uint32_t um3(uint32_t a, uint32_t b, uint32_t c) { return um(um(a, b), c); }

// merge sorted pair (s0<=s1) into sorted-10 kk
__device__ __forceinline__ void mrg2(uint32_t* kk, uint32_t s0, uint32_t s1) {
    uint32_t n0 = um(kk[0], s0);
    uint32_t n1 = um3(kk[1], ux(kk[0], s0), s1);
    uint32_t n2 = um3(kk[2], ux(kk[1], s0), ux(kk[0], s1));
    uint32_t n3 = um3(kk[3], ux(kk[2], s0), ux(kk[1], s1));
    uint32_t n4 = um3(kk[4], ux(kk[3], s0), ux(kk[2], s1));
    uint32_t n5 = um3(kk[5], ux(kk[4], s0), ux(kk[3], s1));
    uint32_t n6 = um3(kk[6], ux(kk[5], s0), ux(kk[4], s1));
    uint32_t n7 = um3(kk[7], ux(kk[6], s0), ux(kk[5], s1));
    uint32_t n8 = um3(kk[8], ux(kk[7], s0), ux(kk[6], s1));
    uint32_t n9 = um3(kk[9], ux(kk[8], s0), ux(kk[7], s1));
    kk[0]=n0; kk[1]=n1; kk[2]=n2; kk[3]=n3; kk[4]=n4;
    kk[5]=n5; kk[6]=n6; kk[7]=n7; kk[8]=n8; kk[9]=n9;
}

// merge sorted quad (s0<=s1<=s2<=s3) into sorted-10 kk
__device__ __forceinline__ void mrg4(uint32_t* kk, uint32_t s0, uint32_t s1,
                                     uint32_t s2, uint32_t s3) {
    uint32_t n0 = um(kk[0], s0);
    uint32_t n1 = um3(kk[1], ux(kk[0], s0), s1);
    uint32_t n2 = um(um3(kk[2], ux(kk[1], s0), ux(kk[0], s1)), s2);
    uint32_t n3 = um3(um3(kk[3], ux(kk[2], s0), ux(kk[1], s1)), ux(kk[0], s2), s3);
    uint32_t n4 = um3(um3(kk[4], ux(kk[3], s0), ux(kk[2], s1)), ux(kk[1], s2), ux(kk[0], s3));
    uint32_t n5 = um3(um3(kk[5], ux(kk[4], s0), ux(kk[3], s1)), ux(kk[2], s2), ux(kk[1], s3));
    uint32_t n6 = um3(um3(kk[6], ux(kk[5], s0), ux(kk[4], s1)), ux(kk[3], s2), ux(kk[2], s3));
    uint32_t n7 = um3(um3(kk[7], ux(kk[6], s0), ux(kk[5], s1)), ux(kk[4], s2), ux(kk[3], s3));
    uint32_t n8 = um3(um3(kk[8], ux(kk[7], s0), ux(kk[6], s1)), ux(kk[5], s2), ux(kk[4], s3));
    uint32_t n9 = um3(um3(kk[9], ux(kk[8], s0), ux(kk[7], s1)), ux(kk[6], s2), ux(kk[5], s3));
    kk[0]=n0; kk[1]=n1; kk[2]=n2; kk[3]=n3; kk[4]=n4;
    kk[5]=n5; kk[6]=n6; kk[7]=n7; kk[8]=n8; kk[9]=n9;
}

// sort 4 keys ascending: 5-CE network
__device__ __forceinline__ void srt4(uint32_t& a, uint32_t& b, uint32_t& c, uint32_t& d) {
    uint32_t t0 = um(a, b), t1 = ux(a, b), t2 = um(c, d), t3 = ux(c, d);
    uint32_t s0 = um(t0, t2), m0 = ux(t0, t2), m1 = um(t1, t3), s3 = ux(t1, t3);
    a = s0; b = um(m0, m1); c = ux(m0, m1); d = s3;
}

// sorted ascending top-10 insert: 19 min/max ops, chain depth 2
__device__ __forceinline__ void ins10(uint32_t* kk, uint32_t x) {
    uint32_t t0 = kk[0];
    kk[0] = um(kk[0], x);
    #pragma unroll
    for (int r = 1; r < 10; ++r) {
        uint32_t xr = ux(t0, x);
        t0 = kk[r];
        kk[r] = um(kk[r], xr);
    }
}

__device__ __forceinline__ uint32_t dkey(const float4& c, float px, float py,
                                         float pz, float pa, int idx) {
    float dot = fmaf(pz, c.z, fmaf(py, c.y, px * c.x));
    float dd = fmaxf(fmaf(-2.f, dot, pa + c.w), 0.f);
    return (__float_as_uint(dd) & 0xFFFFF000u) | (uint32_t)idx;
}

// ---------------- K0: prep ----------------
__global__ __launch_bounds__(256) void k_prep(const float* __restrict__ data,
                                              float* __restrict__ out,
                                              float4* __restrict__ cand4) {
    int t = blockIdx.x * 256 + threadIdx.x;   // BB*NN
    float x = data[t * 3], y = data[t * 3 + 1], z = data[t * 3 + 2];
    out[t * 3] = x; out[t * 3 + 1] = y; out[t * 3 + 2] = z;
    cand4[t] = make_float4(x, y, z, x * x + y * y + z * z);
}

// ---------------- K1: stem ----------------
__global__ __launch_bounds__(256) void k_stem(const float* __restrict__ data,
                                              const float* __restrict__ Ws,
                                              const float* __restrict__ bs,
                                              float* __restrict__ f0) {
    int t = blockIdx.x * 256 + threadIdx.x;
    int c = t & 63;
    int r = t >> 6;
    const float* d = data + r * 3;
    float acc = bs[c];
    acc = fmaf(d[0], Ws[c], acc);
    acc = fmaf(d[1], Ws[64 + c], acc);
    acc = fmaf(d[2], Ws[128 + c], acc);
    f0[t] = fmaxf(acc, 0.f);
}

// ---------------- A: exact sorted-10 over subset (first 256 cands, 4x64) ----------------
__global__ __launch_bounds__(256) void k_knn_sub(const float4* __restrict__ cand4,
                                                 uint32_t* __restrict__ pk) {
    int t = threadIdx.x;
    int blk = blockIdx.x;          // BB*16*4 = 512
    int ch = blk & 3;
    int pg = (blk >> 2) & 15;
    int b = blk >> 6;
    const float4* cb = cand4 + b * NN;
    int c0 = ch * 64;
    int q = b * NN + pg * 256 + t;
    float4 me = cb[pg * 256 + t];
    float px = me.x, py = me.y, pz = me.z, pa = me.w;
    uint32_t kk[10];
    #pragma unroll
    for (int r = 0; r < 10; ++r) kk[r] = 0xFFFFFF00u + r;
    for (int j = 0; j < 64; j += 4) {
        uint32_t ka = dkey(cb[c0 + j],     px, py, pz, pa, c0 + j);
        uint32_t kb = dkey(cb[c0 + j + 1], px, py, pz, pa, c0 + j + 1);
        uint32_t kc = dkey(cb[c0 + j + 2], px, py, pz, pa, c0 + j + 2);
        uint32_t kd = dkey(cb[c0 + j + 3], px, py, pz, pa, c0 + j + 3);
        srt4(ka, kb, kc, kd);
        mrg4(kk, ka, kb, kc, kd);
    }
    #pragma unroll
    for (int r = 0; r < 10; ++r)
        pk[(ch * 10 + r) * (BB * NN) + q] = kk[r];
}

// ---------------- B: threshold filter scan ----------------
// T = exact 10th-smallest subset key (upper bound of global 10th). Survivors
// (key <= T, exact uint compare) superset the true top-10. Store u16 indices.
__global__ __launch_bounds__(256) void k_knn_filt(const float4* __restrict__ cand4,
                                                  const uint32_t* __restrict__ pk,
                                                  unsigned short* __restrict__ sk,
                                                  unsigned short* __restrict__ cnts) {
    int t = threadIdx.x;
    int blk = blockIdx.x;          // BB*16*4 = 512
    int ch = blk & 3;
    int pg = (blk >> 2) & 15;
    int b = blk >> 6;
    const float4* cb = cand4 + b * NN;
    int q = b * NN + pg * 256 + t;
    float4 me = cb[pg * 256 + t];
    float px = me.x, py = me.y, pz = me.z, pa = me.w;
    uint32_t kk[10];
    #pragma unroll
    for (int r = 0; r < 10; ++r) kk[r] = pk[r * (BB * NN) + q];
    for (int s = 1; s < 4; ++s) {
        uint32_t sv[10];
        #pragma unroll
        for (int r = 0; r < 10; ++r) sv[r] = pk[(s * 10 + r) * (BB * NN) + q];
        mrg4(kk, sv[0], sv[1], sv[2], sv[3]);
        mrg4(kk, sv[4], sv[5], sv[6], sv[7]);
        mrg2(kk, sv[8], sv[9]);
    }
    uint32_t T = kk[9];
    int c0 = ch * 1024;
    uint32_t cnt = 0;
    for (int j = 0; j < 1024; ++j) {
        uint32_t key = dkey(cb[c0 + j], px, py, pz, pa, c0 + j);
        if (key <= T) {
            if (cnt < SCAP) sk[(ch * SCAP + cnt) * (BB * NN) + q] = (unsigned short)(c0 + j);
            cnt++;
        }
    }
    cnts[ch * (BB * NN) + q] = (unsigned short)cnt;
}

// ---------------- C1: per-(query,chunk) survivor ladder -> sorted-10 partial ----------------
// 4x32768 threads (512 blocks, 8 waves/CU). x4-unrolled independent loads
// (4 sk reads -> 4 gathers -> srt4+mrg4) for latency hiding.
__global__ __launch_bounds__(256) void k_knn_red(const float4* __restrict__ cand4,
                                                 const unsigned short* __restrict__ sk,
                                                 const unsigned short* __restrict__ cnts,
                                                 uint32_t* __restrict__ p10) {
    int t = blockIdx.x * 256 + threadIdx.x;   // 4 * BB*NN
    int ch = t >> 17;                         // BB*NN = 32768 = 1<<15; 4 chunks -> t>>15
    int q = t & (BB * NN - 1);
    ch = (t >> 15) & 3;
    int b = q >> 12;
    const float4* cb = cand4 + b * NN;
    float4 me = cb[q & (NN - 1)];
    float px = me.x, py = me.y, pz = me.z, pa = me.w;
    uint32_t kk[10];
    #pragma unroll
    for (int r = 0; r < 10; ++r) kk[r] = 0xFFFFFF00u + r;
    int cnt = cnts[ch * (BB * NN) + q];
    if (cnt <= SCAP) {
        int s = 0;
        for (; s + 4 <= cnt; s += 4) {
            int i0 = sk[(ch * SCAP + s)     * (BB * NN) + q];
            int i1 = sk[(ch * SCAP + s + 1) * (BB * NN) + q];
            int i2 = sk[(ch * SCAP + s + 2) * (BB * NN) + q];
            int i3 = sk[(ch * SCAP + s + 3) * (BB * NN) + q];
            uint32_t k0 = dkey(cb[i0], px, py, pz, pa, i0);
            uint32_t k1 = dkey(cb[i1], px, py, pz, pa, i1);
            uint32_t k2 = dkey(cb[i2], px, py, pz, pa, i2);
            uint32_t k3 = dkey(cb[i3], px, py, pz, pa, i3);
            srt4(k0, k1, k2, k3);
            mrg4(kk, k0, k1, k2, k3);
        }
        for (; s < cnt; ++s) {
            int idx = sk[(ch * SCAP + s) * (BB * NN) + q];
            ins10(kk, dkey(cb[idx], px, py, pz, pa, idx));
        }
    } else {
        // essentially-never overflow: exact exhaustive scan of this chunk
        int c0 = ch * 1024;
        for (int j = 0; j < 1024; ++j)
            ins10(kk, dkey(cb[c0 + j], px, py, pz, pa, c0 + j));
    }
    #pragma unroll
    for (int r = 0; r < 10; ++r)
        p10[(ch * 10 + r) * (BB * NN) + q] = kk[r];
}

// ---------------- C2: merge 4 sorted-10s -> mrg + cov + Jacobi eig + eig-MLP ----------------
__device__ __forceinline__ void jrot(float& app, float& aqq, float& apq,
                                     float& arp, float& arq) {
    float ap = apq;
    if (fabsf(ap) > 1e-32f) {
        float th = (aqq - app) / (2.f * ap);
        float t = 1.f / (fabsf(th) + sqrtf(th * th + 1.f));
        t = th < 0.f ? -t : t;
        float c = 1.f / sqrtf(t * t + 1.f);
        float s = t * c;
        app = app - t * ap;
        aqq = aqq + t * ap;
        apq = 0.f;
        float rp = arp, rq = arq;
        arp = c * rp - s * rq;
        arq = s * rp + c * rq;
    }
}

__global__ __launch_bounds__(256) void k_knn_eig(const float4* __restrict__ cand4,
                                                 const uint32_t* __restrict__ p10,
                                                 uint32_t* __restrict__ mrg,
                                                 const float* __restrict__ We1,
                                                 const float* __restrict__ be1,
                                                 const float* __restrict__ We2,
                                                 const float* __restrict__ be2,
                                                 float* __restrict__ ef) {
    int q = blockIdx.x * 256 + threadIdx.x;   // B*N
    int b = q >> 12;
    const float4* cb = cand4 + b * NN;
    uint32_t kk[10];
    #pragma unroll
    for (int r = 0; r < 10; ++r) kk[r] = p10[r * (BB * NN) + q];
    for (int ch = 1; ch < 4; ++ch) {
        uint32_t s[10];
        #pragma unroll
        for (int r = 0; r < 10; ++r) s[r] = p10[(ch * 10 + r) * (BB * NN) + q];
        mrg4(kk, s[0], s[1], s[2], s[3]);
        mrg4(kk, s[4], s[5], s[6], s[7]);
        mrg2(kk, s[8], s[9]);
    }
    #pragma unroll
    for (int r = 0; r < 10; ++r)
        mrg[r * (BB * NN) + q] = kk[r];     // merged sorted-10 for k_sa
    float xs[10], ys[10], zs[10];
    float mx = 0.f, my = 0.f, mz = 0.f;
    #pragma unroll
    for (int r = 0; r < 10; ++r) {
        int n = (int)(kk[r] & 0xFFFu);
        float4 cr = cb[n];
        xs[r] = cr.x; ys[r] = cr.y; zs[r] = cr.z;
        mx += xs[r]; my += ys[r]; mz += zs[r];
    }
    mx *= 0.1f; my *= 0.1f; mz *= 0.1f;
    float a00 = 0, a01 = 0, a02 = 0, a11 = 0, a12 = 0, a22 = 0;
    #pragma unroll
    for (int r = 0; r < 10; ++r) {
        float x = xs[r] - mx, y = ys[r] - my, z = zs[r] - mz;
        a00 = fmaf(x, x, a00); a01 = fmaf(x, y, a01); a02 = fmaf(x, z, a02);
        a11 = fmaf(y, y, a11); a12 = fmaf(y, z, a12); a22 = fmaf(z, z, a22);
    }
    a00 *= 0.1f; a01 *= 0.1f; a02 *= 0.1f; a11 *= 0.1f; a12 *= 0.1f; a22 *= 0.1f;
    #pragma unroll
    for (int sweep = 0; sweep < 6; ++sweep) {
        jrot(a00, a11, a01, a02, a12);
        jrot(a00, a22, a02, a01, a12);
        jrot(a11, a22, a12, a01, a02);
    }
    float e0 = a00, e1 = a11, e2 = a22, tmp;
    if (e0 > e1) { tmp = e0; e0 = e1; e1 = tmp; }
    if (e1 > e2) { tmp = e1; e1 = e2; e2 = tmp; }
    if (e0 > e1) { tmp = e0; e0 = e1; e1 = tmp; }
    float tt[4];
    #pragma unroll
    for (int i = 0; i < 4; ++i) {
        float v = be1[i];
        v = fmaf(e0, We1[i], v);
        v = fmaf(e1, We1[4 + i], v);
        v = fmaf(e2, We1[8 + i], v);
        tt[i] = fmaxf(v, 0.f);
    }
    #pragma unroll
    for (int i = 0; i < 4; ++i) {
        float v = be2[i];
        v = fmaf(tt[0], We2[i], v);
        v = fmaf(tt[1], We2[4 + i], v);
        v = fmaf(tt[2], We2[8 + i], v);
        v = fmaf(tt[3], We2[12 + i], v);
        ef[q * 4 + i] = v;
    }
}

// ---------------- K2: ball query (via merged 10-NN) + SA MLP + maxpool ----------------
__global__ __launch_bounds__(256) void k_sa(const float4* __restrict__ cand4,
                                            const float* __restrict__ data,
                                            const float* __restrict__ f0,
                                            const uint32_t* __restrict__ mrg,
                                            const float* __restrict__ Wsa,
                                            const float* __restrict__ bsa,
                                            float* __restrict__ fsub) {
    __shared__ float2 sW[67 * 64];
    __shared__ int sIdx[4][NS];
    for (int i = threadIdx.x; i < 67 * 64; i += 256) {
        int k = i >> 6, c = i & 63;
        sW[i] = make_float2(Wsa[k * 128 + c], Wsa[k * 128 + 64 + c]);
    }
    __syncthreads();
    int wv = threadIdx.x >> 6, lane = threadIdx.x & 63;
    int gm = blockIdx.x * 4 + wv;
    if (gm >= BB * MM) return;
    int b = gm / MM, m = gm - b * MM;
    const float4* cb4 = cand4 + b * NN;
    const float* db = data + b * NN * 3;
    float4 cen = cb4[3 * m];
    float cx = cen.x, cy = cen.y, cz = cen.z, sa = cen.w;

    int cnt;
    bool fallback;
    {
        float d2l = 1e30f;
        int idxl = 0;
        if (lane < 10) {
            uint32_t key = mrg[lane * (BB * NN) + b * NN + 3 * m];
            idxl = (int)(key & 0xFFFu);
            float4 c = cb4[idxl];
            float dot = fmaf(cz, c.z, fmaf(cy, c.y, cx * c.x));
            d2l = (sa + c.w) - 2.f * dot;
        }
        bool valid = (lane < 10) && (d2l < RAD2);
        unsigned long long mask = __ballot(valid);
        if (valid) sIdx[wv][__popcll(mask & ((1ull << lane) - 1ull))] = idxl;
        cnt = __popcll(mask);
        fallback = rl(d2l, 9) < RAD2 * 1.0005f;
    }
    if (fallback) {
        cnt = 0;
        for (int base = 0; base < NN; base += 64) {
            int n = base + lane;
            float4 c = cb4[n];
            float dot = fmaf(cz, c.z, fmaf(cy, c.y, cx * c.x));
            float d2 = (sa + c.w) - 2.f * dot;
            bool valid = d2 < RAD2;
            unsigned long long mask = __ballot(valid);
            if (valid) {
                int pos = cnt + __popcll(mask & ((1ull << lane) - 1ull));
                if (pos < NS) sIdx[wv][pos] = n;
            }
            cnt += __popcll(mask);
            if (cnt >= NS) break;
        }
    }
    int scnt = cnt < NS ? cnt : NS;

    float cl = lane == 0 ? cx : (lane == 1 ? cy : cz);
    float hb0 = bsa[lane], hb1 = bsa[64 + lane];
    float m0 = 0.f, m1 = 0.f;

    for (int s0 = 0; s0 < scnt; s0 += 4) {
        float fr[4], fr2[4];
        #pragma unroll
        for (int u = 0; u < 4; ++u) {
            int s = s0 + u;
            if (s >= scnt) s = 0;
            int nj = sIdx[wv][s];
            int fb = (b * NN + nj) * 64;
            float v;
            if (lane >= 3) v = f0[fb + lane - 3];
            else           v = (db[nj * 3 + lane] - cl) * 10.0f;
            fr[u] = v;
            fr2[u] = (lane < 3) ? f0[fb + 61 + lane] : 0.f;
        }
        float h0[4], h1[4];
        #pragma unroll
        for (int u = 0; u < 4; ++u) { h0[u] = hb0; h1[u] = hb1; }
        for (int k = 0; k < 64; ++k) {
            float2 w = sW[k * 64 + lane];
            #pragma unroll
            for (int u = 0; u < 4; ++u) {
                float fv = rl(fr[u], k);
                h0[u] = fmaf(fv, w.x, h0[u]);
                h1[u] = fmaf(fv, w.y, h1[u]);
            }
        }
        #pragma unroll
        for (int k = 64; k < 67; ++k) {
            float2 w = sW[k * 64 + lane];
            #pragma unroll
            for (int u = 0; u < 4; ++u) {
                float fv = rl(fr2[u], k - 64);
                h0[u] = fmaf(fv, w.x, h0[u]);
                h1[u] = fmaf(fv, w.y, h1[u]);
            }
        }
        #pragma unroll
        for (int u = 0; u < 4; ++u) {
            m0 = fmaxf(m0, fmaxf(h0[u], 0.f));
            m1 = fmaxf(m1, fmaxf(h1[u], 0.f));
        }
    }
    fsub[gm * 128 + lane] = m0;
    fsub[gm * 128 + 64 + lane] = m1;
}

// ---------------- K3: 3-NN among centers + inverse-distance interp ----------------
__global__ __launch_bounds__(512) void k_interp(const float4* __restrict__ cand4,
                                                const float* __restrict__ fsub,
                                                float* __restrict__ itp) {
    __shared__ float4 sC[MM];
    __shared__ float sMD[8][64][3];
    __shared__ int   sMI[8][64][3];
    __shared__ float sWts[64][3];
    __shared__ int   sNbr[64][3];
    int t = threadIdx.x, wv = t >> 6, lane = t & 63;
    int blk = blockIdx.x;
    int b = blk >> 6;
    int pbase = (blk & 63) * 64;
    const float4* cb4 = cand4 + b * NN;
    for (int m = t; m < MM; m += 512) sC[m] = cb4[3 * m];
    __syncthreads();
    int p = pbase + lane;
    float4 pm = cb4[p];
    float px = pm.x, py = pm.y, pz = pm.z, pa = pm.w;
    float d0 = 1e30f, d1 = 1e30f, d2v = 1e30f;
    int n0 = 0, n1 = 0, n2 = 0;
    int ms = wv * 171, me = ms + 171 < MM ? ms + 171 : MM;
    for (int m = ms; m < me; ++m) {
        float4 c = sC[m];
        float dd = (pa + c.w) - 2.f * (px * c.x + py * c.y + pz * c.z);
        if (dd < d2v) {
            if (dd < d1) {
                d2v = d1; n2 = n1;
                if (dd < d0) { d1 = d0; n1 = n0; d0 = dd; n0 = m; }
                else         { d1 = dd; n1 = m; }
            } else { d2v = dd; n2 = m; }
        }
    }
    sMD[wv][lane][0] = d0; sMD[wv][lane][1] = d1; sMD[wv][lane][2] = d2v;
    sMI[wv][lane][0] = n0; sMI[wv][lane][1] = n1; sMI[wv][lane][2] = n2;
    __syncthreads();
    if (wv == 0) {
        d0 = sMD[0][lane][0]; d1 = sMD[0][lane][1]; d2v = sMD[0][lane][2];
        n0 = sMI[0][lane][0]; n1 = sMI[0][lane][1]; n2 = sMI[0][lane][2];
        for (int w = 1; w < 8; ++w) {
            #pragma unroll
            for (int r = 0; r < 3; ++r) {
                float dd = sMD[w][lane][r];
                int mm = sMI[w][lane][r];
                if (dd < d2v) {
                    if (dd < d1) {
                        d2v = d1; n2 = n1;
                        if (dd < d0) { d1 = d0; n1 = n0; d0 = dd; n0 = mm; }
                        else         { d1 = dd; n1 = mm; }
                    } else { d2v = dd; n2 = mm; }
                }
            }
        }
        float w0 = 1.f / (d0 + 1e-8f), w1 = 1.f / (d1 + 1e-8f), w2 = 1.f / (d2v + 1e-8f);
        float ws = w0 + w1 + w2;
        sWts[lane][0] = w0 / ws; sWts[lane][1] = w1 / ws; sWts[lane][2] = w2 / ws;
        sNbr[lane][0] = n0; sNbr[lane][1] = n1; sNbr[lane][2] = n2;
    }
    __syncthreads();
    for (int i = wv * 8; i < wv * 8 + 8; ++i) {
        float a0 = sWts[i][0], a1 = sWts[i][1], a2 = sWts[i][2];
        const float* r0 = fsub + (b * MM + sNbr[i][0]) * 128;
        const float* r1 = fsub + (b * MM + sNbr[i][1]) * 128;
        const float* r2 = fsub + (b * MM + sNbr[i][2]) * 128;
        float v0 = fmaf(a2, r2[lane], fmaf(a1, r1[lane], a0 * r0[lane]));
        float v1 = fmaf(a2, r2[64 + lane], fmaf(a1, r1[64 + lane], a0 * r0[64 + lane]));
        int row = b * NN + pbase + i;
        itp[row * 128 + lane] = v0;
        itp[row * 128 + 64 + lane] = v1;
    }
}

// ---------------- K5: f = relu([interp, f0] @ W_fp + b_fp) ----------------
__global__ __launch_bounds__(256) void k_fp(const float* __restrict__ itp,
                                            const float* __restrict__ f0,
                                            const float* __restrict__ W,
                                            const float* __restrict__ bias,
                                            float* __restrict__ outf) {
    __shared__ float sW[192 * 64];
    for (int i = threadIdx.x; i < 192 * 64; i += 256) sW[i] = W[i];
    __syncthreads();
    int lane = threadIdx.x & 63;
    int wv = threadIdx.x >> 6;
    float bb = bias[lane];
    int rowbase = blockIdx.x * 64 + wv * 16;
    for (int it = 0; it < 4; ++it) {
        int r = rowbase + it * 4;
        float fa[4], fbv[4], fc[4], acc[4];
        #pragma unroll
        for (int u = 0; u < 4; ++u) {
            fa[u]  = itp[(r + u) * 128 + lane];
            fbv[u] = itp[(r + u) * 128 + 64 + lane];
            fc[u]  = f0[(r + u) * 64 + lane];
            acc[u] = bb;
        }
        #pragma unroll
        for (int k = 0; k < 192; ++k) {
            float w = sW[k * 64 + lane];
            #pragma unroll
            for (int u = 0; u < 4; ++u) {
                float fv = k < 64 ? rl(fa[u], k)
                         : (k < 128 ? rl(fbv[u], k - 64) : rl(fc[u], k - 128));
                acc[u] = fmaf(fv, w, acc[u]);
            }
        }
        #pragma unroll
        for (int u = 0; u < 4; ++u)
            outf[(r + u) * 64 + lane] = fmaxf(acc[u], 0.f);
    }
}

// ---------------- K6: zc = [f, ef] @ W_fin + b_fin ----------------
__global__ __launch_bounds__(256) void k_fin(const float* __restrict__ fb,
                                             const float* __restrict__ efb,
                                             const float* __restrict__ W,
                                             const float* __restrict__ bias,
                                             float* __restrict__ zc) {
    __shared__ float sW[68 * 64];
    for (int i = threadIdx.x; i < 68 * 64; i += 256) sW[i] = W[i];
    __syncthreads();
    int lane = threadIdx.x & 63;
    int wv = threadIdx.x >> 6;
    float bb = bias[lane];
    int rowbase = blockIdx.x * 64 + wv * 16;
    for (int it = 0; it < 4; ++it) {
        int r = rowbase + it * 4;
        float fa[4], fe[4], acc[4];
        #pragma unroll
        for (int u = 0; u < 4; ++u) {
            fa[u] = fb[(r + u) * 64 + lane];
            fe[u] = (lane < 4) ? efb[(r + u) * 4 + lane] : 0.f;
            acc[u] = bb;
        }
        #pragma unroll
        for (int k = 0; k < 68; ++k) {
            float w = sW[k * 64 + lane];
            #pragma unroll
            for (int u = 0; u < 4; ++u) {
                float fv = k < 64 ? rl(fa[u], k) : rl(fe[u], k - 64);
                acc[u] = fmaf(fv, w, acc[u]);
            }
        }
        #pragma unroll
        for (int u = 0; u < 4; ++u)
            zc[(r + u) * 64 + lane] = acc[u];
    }
}

// ---------------- K7: batchnorm stats, two-stage ----------------
__global__ __launch_bounds__(256) void k_stats1(const float* __restrict__ zc,
                                                float* __restrict__ pp) {
    int t = threadIdx.x;
    int c = t & 63, r4 = t >> 6;
    float s = 0.f, sq = 0.f;
    int base = blockIdx.x * 512;
    for (int i = 0; i < 128; ++i) {
        float v = zc[(base + i * 4 + r4) * 64 + c];
        s += v;
        sq = fmaf(v, v, sq);
    }
    __shared__ float ls[256], lq[256];
    ls[t] = s; lq[t] = sq;
    __syncthreads();
    if (t < 64) {
        float st = ls[t] + ls[t + 64] + ls[t + 128] + ls[t + 192];
        float qt = lq[t] + lq[t + 64] + lq[t + 128] + lq[t + 192];
        pp[blockIdx.x * 128 + t] = st;
        pp[blockIdx.x * 128 + 64 + t] = qt;
    }
}

__global__ __launch_bounds__(64) void k_stats2(const float* __restrict__ pp,
                                               const float* __restrict__ gamma,
                                               const float* __restrict__ beta,
                                               float* __restrict__ ss) {
    int c = threadIdx.x;
    float s = 0.f, sq = 0.f;
    for (int k = 0; k < 64; ++k) {
        s += pp[k * 128 + c];
        sq += pp[k * 128 + 64 + c];
    }
    const float inv = 1.f / (float)(BB * NN);
    float mu = s * inv;
    float var = sq * inv - mu * mu;
    float sc = gamma[c] / sqrtf(var + 1e-5f);
    ss[c] = sc;
    ss[64 + c] = beta[c] - mu * sc;
}

// ---------------- K8: normalize + relu + transpose ----------------
__global__ __launch_bounds__(256) void k_norm_t(const float* __restrict__ zc,
                                                const float* __restrict__ ss,
                                                float* __restrict__ out) {
    __shared__ float sT[64][65];
    int blk = blockIdx.x;
    int b = blk >> 6;
    int nbase = (blk & 63) * 64;
    int c = threadIdx.x & 63;
    int r4 = threadIdx.x >> 6;
    float sc = ss[c], sh = ss[64 + c];
    #pragma unroll
    for (int i = 0; i < 16; ++i) {
        int nr = i * 4 + r4;
        float v = zc[(b * NN + nbase + nr) * 64 + c];
        sT[nr][c] = fmaxf(fmaf(v, sc, sh), 0.f);
    }
    __syncthreads();
    int nn = threadIdx.x & 63;
    #pragma unroll
    for (int i = 0; i < 16; ++i) {
        int cc = i * 4 + r4;
        out[BB * NN * 3 + (b * 64 + cc) * NN + nbase + nn] = sT[nn][cc];
    }
}

extern "C" void kernel_launch(void* const* d_in, const int* in_sizes, int n_in,
                              void* d_out, int out_size, void* d_ws, size_t ws_size,
                              hipStream_t stream) {
    const float* data = (const float*)d_in[0];
    const float* Wst  = (const float*)d_in[2];
    const float* bst  = (const float*)d_in[3];
    const float* Wsa  = (const float*)d_in[4];
    const float* bsa  = (const float*)d_in[5];
    const float* Wfp  = (const float*)d_in[6];
    const float* bfp  = (const float*)d_in[7];
    const float* We1  = (const float*)d_in[8];
    const float* be1  = (const float*)d_in[9];
    const float* We2  = (const float*)d_in[10];
    const float* be2  = (const float*)d_in[11];
    const float* Wfin = (const float*)d_in[12];
    const float* bfin = (const float*)d_in[13];
    const float* gamma = (const float*)d_in[14];
    const float* beta  = (const float*)d_in[15];
    float* out = (float*)d_out;

    // layout (floats)
    float* f0   = (float*)d_ws;            // 2,097,152
    float* fsub = f0 + 2097152;            // 1,398,784
    float* efb  = fsub + 1398784;          //   131,072
    float* zc   = efb + 131072;            // 2,097,152 (aliased by p10 early)
    float* ss   = zc + 2097152;            //       128
    float* pp   = ss + 128;                //     8,192
    float* cntf = pp + 8192;               //    65,536 (cnts u16: 4*32768*2B)
    float4* cand4 = (float4*)(cntf + 65536);               // 131,072 floats
    uint32_t* mrgb = (uint32_t*)((float*)cand4 + 131072);  // 1,310,720 u32
    float* itp  = (float*)mrgb + 1310720;  // 4,194,304
    float* fb   = itp + 4194304;           // 2,097,152
    // aliases (each consumed before its host buffer is written):
    uint32_t* pkk = (uint32_t*)mrgb;             // A->B; dead before C2 writes mrgb
    unsigned short* sk = (unsigned short*)itp;   // B->C1; dead before k_interp/k_fp
    unsigned short* cnts = (unsigned short*)cntf;
    uint32_t* p10 = (uint32_t*)zc;               // C1->C2; dead before k_fin writes zc

    k_prep<<<(BB * NN) / 256, 256, 0, stream>>>(data, out, cand4);
    k_stem<<<(BB * NN * 64) / 256, 256, 0, stream>>>(data, Wst, bst, f0);
    k_knn_sub<<<BB * 16 * 4, 256, 0, stream>>>(cand4, pkk);
    k_knn_filt<<<BB * 16 * 4, 256, 0, stream>>>(cand4, pkk, sk, cnts);
    k_knn_red<<<(4 * BB * NN) / 256, 256, 0, stream>>>(cand4, sk, cnts, p10);
    k_knn_eig<<<(BB * NN) / 256, 256, 0, stream>>>(cand4, p10, mrgb,
                                                   We1, be1, We2, be2, efb);
    k_sa<<<(BB * MM + 3) / 4, 256, 0, stream>>>(cand4, data, f0, mrgb, Wsa, bsa, fsub);
    k_interp<<<BB * 64, 512, 0, stream>>>(cand4, fsub, itp);
    k_fp<<<512, 256, 0, stream>>>(itp, f0, Wfp, bfp, fb);
    k_fin<<<512, 256, 0, stream>>>(fb, efb, Wfin, bfin, zc);
    k_stats1<<<64, 256, 0, stream>>>(zc, pp);
    k_stats2<<<1, 64, 0, stream>>>(pp, gamma, beta, ss);
    k_norm_t<<<512, 256, 0, stream>>>(zc, ss, out);
}

// Round 11
// 298.251 us; speedup vs baseline: 3.7138x; 1.9931x over previous
//
#include <hip/hip_runtime.h>
#include <stdint.h>

#define BB 8
#define NN 4096
#define MM 1366   // len(arange(0,4096,3))
#define NS 32
#define RAD2 0.01f
#define NCH 16
#define CHUNK (NN/NCH) // 256

static_assert(NCH * CHUNK == NN, "chunking");

__device__ __forceinline__ float rl(float v, int l) {
    return __int_as_float(__builtin_amdgcn_readlane(__float_as_int(v), l));
}
__device__ __forceinline__ uint32_t um(uint32_t a, uint32_t b) { return a < b ? a : b; }
__device__ __forceinline__ uint32_t ux(uint32_t a, uint32_t b) { return a > b ? a : b; }
__device__ __forceinline__ uint32_t um3(uint32_t a, uint32_t b, uint32_t c) { return um(um(a, b), c); }

// merge sorted pair (s0<=s1) into sorted-10 kk
__device__ __forceinline__ void mrg2(uint32_t* kk, uint32_t s0, uint32_t s1) {
    uint32_t n0 = um(kk[0], s0);
    uint32_t n1 = um3(kk[1], ux(kk[0], s0), s1);
    uint32_t n2 = um3(kk[2], ux(kk[1], s0), ux(kk[0], s1));
    uint32_t n3 = um3(kk[3], ux(kk[2], s0), ux(kk[1], s1));
    uint32_t n4 = um3(kk[4], ux(kk[3], s0), ux(kk[2], s1));
    uint32_t n5 = um3(kk[5], ux(kk[4], s0), ux(kk[3], s1));
    uint32_t n6 = um3(kk[6], ux(kk[5], s0), ux(kk[4], s1));
    uint32_t n7 = um3(kk[7], ux(kk[6], s0), ux(kk[5], s1));
    uint32_t n8 = um3(kk[8], ux(kk[7], s0), ux(kk[6], s1));
    uint32_t n9 = um3(kk[9], ux(kk[8], s0), ux(kk[7], s1));
    kk[0]=n0; kk[1]=n1; kk[2]=n2; kk[3]=n3; kk[4]=n4;
    kk[5]=n5; kk[6]=n6; kk[7]=n7; kk[8]=n8; kk[9]=n9;
}

// merge sorted quad (s0<=s1<=s2<=s3) into sorted-10 kk
__device__ __forceinline__ void mrg4(uint32_t* kk, uint32_t s0, uint32_t s1,
                                     uint32_t s2, uint32_t s3) {
    uint32_t n0 = um(kk[0], s0);
    uint32_t n1 = um3(kk[1], ux(kk[0], s0), s1);
    uint32_t n2 = um(um3(kk[2], ux(kk[1], s0), ux(kk[0], s1)), s2);
    uint32_t n3 = um3(um3(kk[3], ux(kk[2], s0), ux(kk[1], s1)), ux(kk[0], s2), s3);
    uint32_t n4 = um3(um3(kk[4], ux(kk[3], s0), ux(kk[2], s1)), ux(kk[1], s2), ux(kk[0], s3));
    uint32_t n5 = um3(um3(kk[5], ux(kk[4], s0), ux(kk[3], s1)), ux(kk[2], s2), ux(kk[1], s3));
    uint32_t n6 = um3(um3(kk[6], ux(kk[5], s0), ux(kk[4], s1)), ux(kk[3], s2), ux(kk[2], s3));
    uint32_t n7 = um3(um3(kk[7], ux(kk[6], s0), ux(kk[5], s1)), ux(kk[4], s2), ux(kk[3], s3));
    uint32_t n8 = um3(um3(kk[8], ux(kk[7], s0), ux(kk[6], s1)), ux(kk[5], s2), ux(kk[4], s3));
    uint32_t n9 = um3(um3(kk[9], ux(kk[8], s0), ux(kk[7], s1)), ux(kk[6], s2), ux(kk[5], s3));
    kk[0]=n0; kk[1]=n1; kk[2]=n2; kk[3]=n3; kk[4]=n4;
    kk[5]=n5; kk[6]=n6; kk[7]=n7; kk[8]=n8; kk[9]=n9;
}

// sort 4 keys ascending: 5-CE network
__device__ __forceinline__ void srt4(uint32_t& a, uint32_t& b, uint32_t& c, uint32_t& d) {
    uint32_t t0 = um(a, b), t1 = ux(a, b), t2 = um(c, d), t3 = ux(c, d);
    uint32_t s0 = um(t0, t2), m0 = ux(t0, t2), m1 = um(t1, t3), s3 = ux(t1, t3);
    a = s0; b = um(m0, m1); c = ux(m0, m1); d = s3;
}

// ---------------- K1: stem (+ prep absorbed as extra blocks) ----------------
__global__ __launch_bounds__(256) void k_stem(const float* __restrict__ data,
                                              const float* __restrict__ Ws,
                                              const float* __restrict__ bs,
                                              float* __restrict__ f0,
                                              float* __restrict__ out,
                                              float4* __restrict__ cand4) {
    int blk = blockIdx.x;
    if (blk >= (BB * NN * 64) / 256) {
        // prep blocks: copy data -> out, build cand4 = (x,y,z,|p|^2)
        int t = (blk - (BB * NN * 64) / 256) * 256 + threadIdx.x;   // BB*NN
        float x = data[t * 3], y = data[t * 3 + 1], z = data[t * 3 + 2];
        out[t * 3] = x; out[t * 3 + 1] = y; out[t * 3 + 2] = z;
        cand4[t] = make_float4(x, y, z, x * x + y * y + z * z);
        return;
    }
    int t = blk * 256 + threadIdx.x;
    int c = t & 63;
    int r = t >> 6;
    const float* d = data + r * 3;
    float acc = bs[c];
    acc = fmaf(d[0], Ws[c], acc);
    acc = fmaf(d[1], Ws[64 + c], acc);
    acc = fmaf(d[2], Ws[128 + c], acc);
    f0[t] = fmaxf(acc, 0.f);
}

// ---------------- K2: ball query (via merged 10-NN) + SA MLP + maxpool ----------------
__global__ __launch_bounds__(256) void k_sa(const float4* __restrict__ cand4,
                                            const float* __restrict__ data,
                                            const float* __restrict__ f0,
                                            const uint32_t* __restrict__ mrg,
                                            const float* __restrict__ Wsa,
                                            const float* __restrict__ bsa,
                                            float* __restrict__ fsub) {
    __shared__ float2 sW[67 * 64];
    __shared__ int sIdx[4][NS];
    for (int i = threadIdx.x; i < 67 * 64; i += 256) {
        int k = i >> 6, c = i & 63;
        sW[i] = make_float2(Wsa[k * 128 + c], Wsa[k * 128 + 64 + c]);
    }
    __syncthreads();
    int wv = threadIdx.x >> 6, lane = threadIdx.x & 63;
    int gm = blockIdx.x * 4 + wv;
    if (gm >= BB * MM) return;
    int b = gm / MM, m = gm - b * MM;
    const float4* cb4 = cand4 + b * NN;
    const float* db = data + b * NN * 3;
    float4 cen = cb4[3 * m];
    float cx = cen.x, cy = cen.y, cz = cen.z, sa = cen.w;

    // fast ball query: exact-d2 filter of the merged 10-NN
    int cnt;
    bool fallback;
    {
        float d2l = 1e30f;
        int idxl = 0;
        if (lane < 10) {
            uint32_t key = mrg[lane * (BB * NN) + b * NN + 3 * m];
            idxl = (int)(key & 0xFFFu);
            float4 c = cb4[idxl];
            float dot = fmaf(cz, c.z, fmaf(cy, c.y, cx * c.x));
            d2l = (sa + c.w) - 2.f * dot;
        }
        bool valid = (lane < 10) && (d2l < RAD2);
        unsigned long long mask = __ballot(valid);
        if (valid) sIdx[wv][__popcll(mask & ((1ull << lane) - 1ull))] = idxl;
        cnt = __popcll(mask);
        fallback = rl(d2l, 9) < RAD2 * 1.0005f;   // ball might exceed top-10
    }
    if (fallback) {
        cnt = 0;
        for (int base = 0; base < NN; base += 64) {
            int n = base + lane;
            float4 c = cb4[n];
            float dot = fmaf(cz, c.z, fmaf(cy, c.y, cx * c.x));
            float d2 = (sa + c.w) - 2.f * dot;
            bool valid = d2 < RAD2;
            unsigned long long mask = __ballot(valid);
            if (valid) {
                int pos = cnt + __popcll(mask & ((1ull << lane) - 1ull));
                if (pos < NS) sIdx[wv][pos] = n;
            }
            cnt += __popcll(mask);
            if (cnt >= NS) break;
        }
    }
    int scnt = cnt < NS ? cnt : NS;

    float cl = lane == 0 ? cx : (lane == 1 ? cy : cz);
    float hb0 = bsa[lane], hb1 = bsa[64 + lane];
    float m0 = 0.f, m1 = 0.f;       // relu outputs >= 0

    for (int s0 = 0; s0 < scnt; s0 += 4) {
        float fr[4], fr2[4];
        #pragma unroll
        for (int u = 0; u < 4; ++u) {
            int s = s0 + u;
            if (s >= scnt) s = 0;          // pad with sample 0 (real, max-safe)
            int nj = sIdx[wv][s];
            int fb = (b * NN + nj) * 64;
            float v;
            if (lane >= 3) v = f0[fb + lane - 3];
            else           v = (db[nj * 3 + lane] - cl) * 10.0f;   // dp = diff/0.1
            fr[u] = v;
            fr2[u] = (lane < 3) ? f0[fb + 61 + lane] : 0.f;
        }
        float h0[4], h1[4];
        #pragma unroll
        for (int u = 0; u < 4; ++u) { h0[u] = hb0; h1[u] = hb1; }
        for (int k = 0; k < 64; ++k) {
            float2 w = sW[k * 64 + lane];
            #pragma unroll
            for (int u = 0; u < 4; ++u) {
                float fv = rl(fr[u], k);
                h0[u] = fmaf(fv, w.x, h0[u]);
                h1[u] = fmaf(fv, w.y, h1[u]);
            }
        }
        #pragma unroll
        for (int k = 64; k < 67; ++k) {
            float2 w = sW[k * 64 + lane];
            #pragma unroll
            for (int u = 0; u < 4; ++u) {
                float fv = rl(fr2[u], k - 64);
                h0[u] = fmaf(fv, w.x, h0[u]);
                h1[u] = fmaf(fv, w.y, h1[u]);
            }
        }
        #pragma unroll
        for (int u = 0; u < 4; ++u) {
            m0 = fmaxf(m0, fmaxf(h0[u], 0.f));
            m1 = fmaxf(m1, fmaxf(h1[u], 0.f));
        }
    }
    fsub[gm * 128 + lane] = m0;
    fsub[gm * 128 + 64 + lane] = m1;
}

// ---------------- K3: 3-NN among centers + inverse-distance interp ----------------
__global__ __launch_bounds__(512) void k_interp(const float4* __restrict__ cand4,
                                                const float* __restrict__ fsub,
                                                float* __restrict__ itp) {
    __shared__ float4 sC[MM];
    __shared__ float sMD[8][64][3];
    __shared__ int   sMI[8][64][3];
    __shared__ float sWts[64][3];
    __shared__ int   sNbr[64][3];
    int t = threadIdx.x, wv = t >> 6, lane = t & 63;
    int blk = blockIdx.x;
    int b = blk >> 6;
    int pbase = (blk & 63) * 64;
    const float4* cb4 = cand4 + b * NN;
    for (int m = t; m < MM; m += 512) sC[m] = cb4[3 * m];
    __syncthreads();
    int p = pbase + lane;
    float4 pm = cb4[p];
    float px = pm.x, py = pm.y, pz = pm.z, pa = pm.w;
    float d0 = 1e30f, d1 = 1e30f, d2v = 1e30f;
    int n0 = 0, n1 = 0, n2 = 0;
    int ms = wv * 171, me = ms + 171 < MM ? ms + 171 : MM;
    for (int m = ms; m < me; ++m) {
        float4 c = sC[m];
        float dd = (pa + c.w) - 2.f * (px * c.x + py * c.y + pz * c.z);
        if (dd < d2v) {
            if (dd < d1) {
                d2v = d1; n2 = n1;
                if (dd < d0) { d1 = d0; n1 = n0; d0 = dd; n0 = m; }
                else         { d1 = dd; n1 = m; }
            } else { d2v = dd; n2 = m; }
        }
    }
    sMD[wv][lane][0] = d0; sMD[wv][lane][1] = d1; sMD[wv][lane][2] = d2v;
    sMI[wv][lane][0] = n0; sMI[wv][lane][1] = n1; sMI[wv][lane][2] = n2;
    __syncthreads();
    if (wv == 0) {
        d0 = sMD[0][lane][0]; d1 = sMD[0][lane][1]; d2v = sMD[0][lane][2];
        n0 = sMI[0][lane][0]; n1 = sMI[0][lane][1]; n2 = sMI[0][lane][2];
        for (int w = 1; w < 8; ++w) {
            #pragma unroll
            for (int r = 0; r < 3; ++r) {
                float dd = sMD[w][lane][r];
                int mm = sMI[w][lane][r];
                if (dd < d2v) {
                    if (dd < d1) {
                        d2v = d1; n2 = n1;
                        if (dd < d0) { d1 = d0; n1 = n0; d0 = dd; n0 = mm; }
                        else         { d1 = dd; n1 = mm; }
                    } else { d2v = dd; n2 = mm; }
                }
            }
        }
        float w0 = 1.f / (d0 + 1e-8f), w1 = 1.f / (d1 + 1e-8f), w2 = 1.f / (d2v + 1e-8f);
        float ws = w0 + w1 + w2;
        sWts[lane][0] = w0 / ws; sWts[lane][1] = w1 / ws; sWts[lane][2] = w2 / ws;
        sNbr[lane][0] = n0; sNbr[lane][1] = n1; sNbr[lane][2] = n2;
    }
    __syncthreads();
    for (int i = wv * 8; i < wv * 8 + 8; ++i) {
        float a0 = sWts[i][0], a1 = sWts[i][1], a2 = sWts[i][2];
        const float* r0 = fsub + (b * MM + sNbr[i][0]) * 128;
        const float* r1 = fsub + (b * MM + sNbr[i][1]) * 128;
        const float* r2 = fsub + (b * MM + sNbr[i][2]) * 128;
        float v0 = fmaf(a2, r2[lane], fmaf(a1, r1[lane], a0 * r0[lane]));
        float v1 = fmaf(a2, r2[64 + lane], fmaf(a1, r1[64 + lane], a0 * r0[64 + lane]));
        int row = b * NN + pbase + i;
        itp[row * 128 + lane] = v0;
        itp[row * 128 + 64 + lane] = v1;
    }
}

// ---------------- K4a: partial top-10 NN, batch-4 sort + merge ladder ----------------
__global__ __launch_bounds__(256) void k_knn_part(const float4* __restrict__ cand4,
                                                  uint32_t* __restrict__ pk) {
    int t = threadIdx.x;
    int blk = blockIdx.x;          // BB * 16 * NCH = 2048
    int ch = blk & (NCH - 1);
    int pg = (blk >> 4) & 15;
    int b = blk >> 8;
    const float4* cb = cand4 + b * NN;
    int c0 = ch * CHUNK;
    int p = pg * 256 + t;
    float4 me = cb[p];
    float px = me.x, py = me.y, pz = me.z, pa = me.w;
    uint32_t kk[10];
    #pragma unroll
    for (int r = 0; r < 10; ++r) kk[r] = 0xFFFFFF00u + r;   // ascending sentinels
    for (int j = 0; j < CHUNK; j += 4) {
        float4 ca = cb[c0 + j];
        float4 cbv = cb[c0 + j + 1];
        float4 cc = cb[c0 + j + 2];
        float4 cd = cb[c0 + j + 3];
        float da = fmaxf(fmaf(-2.f, fmaf(pz, ca.z, fmaf(py, ca.y, px * ca.x)), pa + ca.w), 0.f);
        float db_ = fmaxf(fmaf(-2.f, fmaf(pz, cbv.z, fmaf(py, cbv.y, px * cbv.x)), pa + cbv.w), 0.f);
        float dc = fmaxf(fmaf(-2.f, fmaf(pz, cc.z, fmaf(py, cc.y, px * cc.x)), pa + cc.w), 0.f);
        float dd = fmaxf(fmaf(-2.f, fmaf(pz, cd.z, fmaf(py, cd.y, px * cd.x)), pa + cd.w), 0.f);
        uint32_t ka = (__float_as_uint(da) & 0xFFFFF000u) | (uint32_t)(c0 + j);
        uint32_t kb = (__float_as_uint(db_) & 0xFFFFF000u) | (uint32_t)(c0 + j + 1);
        uint32_t kc = (__float_as_uint(dc) & 0xFFFFF000u) | (uint32_t)(c0 + j + 2);
        uint32_t kd = (__float_as_uint(dd) & 0xFFFFF000u) | (uint32_t)(c0 + j + 3);
        srt4(ka, kb, kc, kd);
        mrg4(kk, ka, kb, kc, kd);
    }
    int gp = b * NN + p;
    #pragma unroll
    for (int r = 0; r < 10; ++r)
        pk[(ch * 10 + r) * (BB * NN) + gp] = kk[r];   // SoA coalesced, sorted per chunk
}

// ---------------- K4b: merge packed top-10 (store merged), cov, Jacobi eig, eig-MLP ----------------
__device__ __forceinline__ void jrot(float& app, float& aqq, float& apq,
                                     float& arp, float& arq) {
    float ap = apq;
    if (fabsf(ap) > 1e-32f) {
        float th = (aqq - app) / (2.f * ap);
        float t = 1.f / (fabsf(th) + sqrtf(th * th + 1.f));
        t = th < 0.f ? -t : t;
        float c = 1.f / sqrtf(t * t + 1.f);
        float s = t * c;
        app = app - t * ap;
        aqq = aqq + t * ap;
        apq = 0.f;
        float rp = arp, rq = arq;
        arp = c * rp - s * rq;
        arq = s * rp + c * rq;
    }
}

__global__ __launch_bounds__(256) void k_knn_eig(const float4* __restrict__ cand4,
                                                 const uint32_t* __restrict__ pk,
                                                 uint32_t* __restrict__ mrg,
                                                 const float* __restrict__ We1,
                                                 const float* __restrict__ be1,
                                                 const float* __restrict__ We2,
                                                 const float* __restrict__ be2,
                                                 float* __restrict__ ef) {
    int t = blockIdx.x * 256 + threadIdx.x;   // B*N
    int b = t >> 12;
    const float4* cb = cand4 + b * NN;
    uint32_t kk[10];
    #pragma unroll
    for (int r = 0; r < 10; ++r) kk[r] = pk[r * (BB * NN) + t];   // chunk 0, sorted
    for (int ch = 1; ch < NCH; ++ch) {
        uint32_t s[10];
        #pragma unroll
        for (int r = 0; r < 10; ++r) s[r] = pk[(ch * 10 + r) * (BB * NN) + t];
        mrg4(kk, s[0], s[1], s[2], s[3]);   // rows already sorted per chunk
        mrg4(kk, s[4], s[5], s[6], s[7]);
        mrg2(kk, s[8], s[9]);
    }
    #pragma unroll
    for (int r = 0; r < 10; ++r)
        mrg[r * (BB * NN) + t] = kk[r];     // merged sorted-10 for k_sa
    float xs[10], ys[10], zs[10];
    float mx = 0.f, my = 0.f, mz = 0.f;
    #pragma unroll
    for (int r = 0; r < 10; ++r) {
        int n = (int)(kk[r] & 0xFFFu);
        float4 cr = cb[n];
        xs[r] = cr.x; ys[r] = cr.y; zs[r] = cr.z;
        mx += xs[r]; my += ys[r]; mz += zs[r];
    }
    mx *= 0.1f; my *= 0.1f; mz *= 0.1f;
    float a00 = 0, a01 = 0, a02 = 0, a11 = 0, a12 = 0, a22 = 0;
    #pragma unroll
    for (int r = 0; r < 10; ++r) {
        float x = xs[r] - mx, y = ys[r] - my, z = zs[r] - mz;
        a00 = fmaf(x, x, a00); a01 = fmaf(x, y, a01); a02 = fmaf(x, z, a02);
        a11 = fmaf(y, y, a11); a12 = fmaf(y, z, a12); a22 = fmaf(z, z, a22);
    }
    a00 *= 0.1f; a01 *= 0.1f; a02 *= 0.1f; a11 *= 0.1f; a12 *= 0.1f; a22 *= 0.1f;
    #pragma unroll
    for (int sweep = 0; sweep < 6; ++sweep) {
        jrot(a00, a11, a01, a02, a12);
        jrot(a00, a22, a02, a01, a12);
        jrot(a11, a22, a12, a01, a02);
    }
    float e0 = a00, e1 = a11, e2 = a22, tmp;
    if (e0 > e1) { tmp = e0; e0 = e1; e1 = tmp; }
    if (e1 > e2) { tmp = e1; e1 = e2; e2 = tmp; }
    if (e0 > e1) { tmp = e0; e0 = e1; e1 = tmp; }
    float tt[4];
    #pragma unroll
    for (int i = 0; i < 4; ++i) {
        float v = be1[i];
        v = fmaf(e0, We1[i], v);
        v = fmaf(e1, We1[4 + i], v);
        v = fmaf(e2, We1[8 + i], v);
        tt[i] = fmaxf(v, 0.f);
    }
    #pragma unroll
    for (int i = 0; i < 4; ++i) {
        float v = be2[i];
        v = fmaf(tt[0], We2[i], v);
        v = fmaf(tt[1], We2[4 + i], v);
        v = fmaf(tt[2], We2[8 + i], v);
        v = fmaf(tt[3], We2[12 + i], v);
        ef[t * 4 + i] = v;
    }
}

// ---------------- K5: f = relu([interp, f0] @ W_fp + b_fp) ----------------
__global__ __launch_bounds__(256) void k_fp(const float* __restrict__ itp,
                                            const float* __restrict__ f0,
                                            const float* __restrict__ W,
                                            const float* __restrict__ bias,
                                            float* __restrict__ outf) {
    __shared__ float sW[192 * 64];
    for (int i = threadIdx.x; i < 192 * 64; i += 256) sW[i] = W[i];
    __syncthreads();
    int lane = threadIdx.x & 63;
    int wv = threadIdx.x >> 6;
    float bb = bias[lane];
    int rowbase = blockIdx.x * 64 + wv * 16;
    for (int it = 0; it < 4; ++it) {
        int r = rowbase + it * 4;
        float fa[4], fbv[4], fc[4], acc[4];
        #pragma unroll
        for (int u = 0; u < 4; ++u) {
            fa[u]  = itp[(r + u) * 128 + lane];
            fbv[u] = itp[(r + u) * 128 + 64 + lane];
            fc[u]  = f0[(r + u) * 64 + lane];
            acc[u] = bb;
        }
        #pragma unroll
        for (int k = 0; k < 192; ++k) {
            float w = sW[k * 64 + lane];
            #pragma unroll
            for (int u = 0; u < 4; ++u) {
                float fv = k < 64 ? rl(fa[u], k)
                         : (k < 128 ? rl(fbv[u], k - 64) : rl(fc[u], k - 128));
                acc[u] = fmaf(fv, w, acc[u]);
            }
        }
        #pragma unroll
        for (int u = 0; u < 4; ++u)
            outf[(r + u) * 64 + lane] = fmaxf(acc[u], 0.f);
    }
}

// ---------------- K6: zc = [f, ef] @ W_fin + b_fin ----------------
__global__ __launch_bounds__(256) void k_fin(const float* __restrict__ fb,
                                             const float* __restrict__ efb,
                                             const float* __restrict__ W,
                                             const float* __restrict__ bias,
                                             float* __restrict__ zc) {
    __shared__ float sW[68 * 64];
    for (int i = threadIdx.x; i < 68 * 64; i += 256) sW[i] = W[i];
    __syncthreads();
    int lane = threadIdx.x & 63;
    int wv = threadIdx.x >> 6;
    float bb = bias[lane];
    int rowbase = blockIdx.x * 64 + wv * 16;
    for (int it = 0; it < 4; ++it) {
        int r = rowbase + it * 4;
        float fa[4], fe[4], acc[4];
        #pragma unroll
        for (int u = 0; u < 4; ++u) {
            fa[u] = fb[(r + u) * 64 + lane];
            fe[u] = (lane < 4) ? efb[(r + u) * 4 + lane] : 0.f;
            acc[u] = bb;
        }
        #pragma unroll
        for (int k = 0; k < 68; ++k) {
            float w = sW[k * 64 + lane];
            #pragma unroll
            for (int u = 0; u < 4; ++u) {
                float fv = k < 64 ? rl(fa[u], k) : rl(fe[u], k - 64);
                acc[u] = fmaf(fv, w, acc[u]);
            }
        }
        #pragma unroll
        for (int u = 0; u < 4; ++u)
            zc[(r + u) * 64 + lane] = acc[u];
    }
}

// ---------------- K7: batchnorm stats, two-stage ----------------
__global__ __launch_bounds__(256) void k_stats1(const float* __restrict__ zc,
                                                float* __restrict__ pp) {
    int t = threadIdx.x;
    int c = t & 63, r4 = t >> 6;
    float s = 0.f, sq = 0.f;
    int base = blockIdx.x * 512;
    for (int i = 0; i < 128; ++i) {
        float v = zc[(base + i * 4 + r4) * 64 + c];
        s += v;
        sq = fmaf(v, v, sq);
    }
    __shared__ float ls[256], lq[256];
    ls[t] = s; lq[t] = sq;
    __syncthreads();
    if (t < 64) {
        float st = ls[t] + ls[t + 64] + ls[t + 128] + ls[t + 192];
        float qt = lq[t] + lq[t + 64] + lq[t + 128] + lq[t + 192];
        pp[blockIdx.x * 128 + t] = st;
        pp[blockIdx.x * 128 + 64 + t] = qt;
    }
}

__global__ __launch_bounds__(64) void k_stats2(const float* __restrict__ pp,
                                               const float* __restrict__ gamma,
                                               const float* __restrict__ beta,
                                               float* __restrict__ ss) {
    int c = threadIdx.x;
    float s = 0.f, sq = 0.f;
    for (int k = 0; k < 64; ++k) {
        s += pp[k * 128 + c];
        sq += pp[k * 128 + 64 + c];
    }
    const float inv = 1.f / (float)(BB * NN);
    float mu = s * inv;
    float var = sq * inv - mu * mu;
    float sc = gamma[c] / sqrtf(var + 1e-5f);
    ss[c] = sc;
    ss[64 + c] = beta[c] - mu * sc;
}

// ---------------- K8: normalize + relu + transpose ----------------
__global__ __launch_bounds__(256) void k_norm_t(const float* __restrict__ zc,
                                                const float* __restrict__ ss,
                                                float* __restrict__ out) {
    __shared__ float sT[64][65];
    int blk = blockIdx.x;
    int b = blk >> 6;
    int nbase = (blk & 63) * 64;
    int c = threadIdx.x & 63;
    int r4 = threadIdx.x >> 6;
    float sc = ss[c], sh = ss[64 + c];
    #pragma unroll
    for (int i = 0; i < 16; ++i) {
        int nr = i * 4 + r4;
        float v = zc[(b * NN + nbase + nr) * 64 + c];
        sT[nr][c] = fmaxf(fmaf(v, sc, sh), 0.f);
    }
    __syncthreads();
    int nn = threadIdx.x & 63;
    #pragma unroll
    for (int i = 0; i < 16; ++i) {
        int cc = i * 4 + r4;
        out[BB * NN * 3 + (b * 64 + cc) * NN + nbase + nn] = sT[nn][cc];
    }
}

extern "C" void kernel_launch(void* const* d_in, const int* in_sizes, int n_in,
                              void* d_out, int out_size, void* d_ws, size_t ws_size,
                              hipStream_t stream) {
    const float* data = (const float*)d_in[0];
    const float* Wst  = (const float*)d_in[2];
    const float* bst  = (const float*)d_in[3];
    const float* Wsa  = (const float*)d_in[4];
    const float* bsa  = (const float*)d_in[5];
    const float* Wfp  = (const float*)d_in[6];
    const float* bfp  = (const float*)d_in[7];
    const float* We1  = (const float*)d_in[8];
    const float* be1  = (const float*)d_in[9];
    const float* We2  = (const float*)d_in[10];
    const float* be2  = (const float*)d_in[11];
    const float* Wfin = (const float*)d_in[12];
    const float* bfin = (const float*)d_in[13];
    const float* gamma = (const float*)d_in[14];
    const float* beta  = (const float*)d_in[15];
    float* out = (float*)d_out;

    // layout (floats): buffers consumed late come last so pkk can alias them
    float* f0   = (float*)d_ws;            // 2,097,152
    float* fsub = f0 + 2097152;            // 1,398,784
    float* efb  = fsub + 1398784;          //   131,072
    float* zc   = efb + 131072;            // 2,097,152
    float* ss   = zc + 2097152;            //       128
    float* pp   = ss + 128;                //     8,192
    float4* cand4 = (float4*)(pp + 8192);  //   131,072 floats, 16B-aligned
    uint32_t* mrgb = (uint32_t*)((float*)cand4 + 131072);   // 1,310,720 u32
    float* itp  = (float*)mrgb + 1310720;  // 4,194,304
    float* fb   = itp + 4194304;           // 2,097,152
    // pkk (16*10*32768 = 5,242,880 u32) aliases itp+fb (6,291,456 floats):
    // fully consumed by k_knn_eig before k_interp/k_fp write itp/fb.
    uint32_t* pkk = (uint32_t*)itp;

    // stem grid: 8192 stem blocks + 128 prep blocks (block-level split)
    k_stem<<<(BB * NN * 64) / 256 + (BB * NN) / 256, 256, 0, stream>>>(
        data, Wst, bst, f0, out, cand4);
    k_knn_part<<<BB * 16 * NCH, 256, 0, stream>>>(cand4, pkk);
    k_knn_eig<<<(BB * NN) / 256, 256, 0, stream>>>(cand4, pkk, mrgb, We1, be1, We2, be2, efb);
    k_sa<<<(BB * MM + 3) / 4, 256, 0, stream>>>(cand4, data, f0, mrgb, Wsa, bsa, fsub);
    k_interp<<<BB * 64, 512, 0, stream>>>(cand4, fsub, itp);
    k_fp<<<512, 256, 0, stream>>>(itp, f0, Wfp, bfp, fb);
    k_fin<<<512, 256, 0, stream>>>(fb, efb, Wfin, bfin, zc);
    k_stats1<<<64, 256, 0, stream>>>(zc, pp);
    k_stats2<<<1, 64, 0, stream>>>(pp, gamma, beta, ss);
    k_norm_t<<<512, 256, 0, stream>>>(zc, ss, out);
}